// Round 1
// baseline (1133.143 us; speedup 1.0000x reference)
//
#include <hip/hip_runtime.h>
#include <stdint.h>

#define NB 64      // batch
#define NP 576     // patches
#define ND 768     // dim
#define NG 64      // groups
#define NN 65      // groups + 1 (cls)
#define NSTEPS 8
#define FLOORV 1.0e-4f
#define EPSV   1.0e-4f
#define DTV    0.1f
#define GAMMAV 0.1f
#define KEEPC  288  // max(1, round(576*0.5))

// ---------------------------------------------------------------- K1: group means
__global__ __launch_bounds__(256) void k_group_means(const float* __restrict__ tokens,
                                                     const float* __restrict__ cls,
                                                     float* __restrict__ nodes,
                                                     const int* __restrict__ ghp,
                                                     const int* __restrict__ gwp) {
    int bx = blockIdx.x;
    int b = bx / NN, n = bx - b * NN;
    int tid = threadIdx.x;
    float* orow = nodes + (size_t)bx * ND;
    if (n == 0) {
        for (int d = tid; d < ND; d += 256) orow[d] = cls[(size_t)b * ND + d];
        return;
    }
    int grid_h = *ghp, grid_w = *gwp;
    int gh = (grid_h + 7) / 8, gw = (grid_w + 7) / 8;
    int g = n - 1, gr = g >> 3, gc = g & 7;
    int r0 = gr * gh, r1 = (gr == 7) ? grid_h : min((gr + 1) * gh, grid_h);
    int c0 = gc * gw, c1 = (gc == 7) ? grid_w : min((gc + 1) * gw, grid_w);
    int cnt = (r1 > r0 && c1 > c0) ? (r1 - r0) * (c1 - c0) : 0;
    float cf = (float)max(cnt, 1);
    const float* tb = tokens + (size_t)b * NP * ND;
    for (int d = tid; d < ND; d += 256) {
        float acc = 0.f;
        for (int r = r0; r < r1; ++r)
            for (int c = c0; c < c1; ++c)
                acc += tb[(size_t)(r * grid_w + c) * ND + d];
        orow[d] = acc / cf;
    }
}

// ---------------------------------------------------------------- K2: proj = nodes @ W^T (NT gemm)
__global__ __launch_bounds__(256) void k_gemm_nt(const float* __restrict__ A,
                                                 const float* __restrict__ Bm,
                                                 float* __restrict__ Cm) {
    __shared__ float As[32][68];
    __shared__ float Bs[32][68];
    int tid = threadIdx.x;
    int m0 = blockIdx.x * 64, n0 = blockIdx.y * 64;
    int tx = tid & 15, ty = tid >> 4;
    float acc[4][4];
#pragma unroll
    for (int i = 0; i < 4; ++i)
#pragma unroll
        for (int j = 0; j < 4; ++j) acc[i][j] = 0.f;
    int lrow = tid >> 3, lq = tid & 7;
    for (int k0 = 0; k0 < ND; k0 += 32) {
#pragma unroll
        for (int l = 0; l < 2; ++l) {
            int row = lrow + l * 32;
            float4 va = *(const float4*)&A[(size_t)(m0 + row) * ND + k0 + lq * 4];
            As[lq * 4 + 0][row] = va.x; As[lq * 4 + 1][row] = va.y;
            As[lq * 4 + 2][row] = va.z; As[lq * 4 + 3][row] = va.w;
            float4 vb = *(const float4*)&Bm[(size_t)(n0 + row) * ND + k0 + lq * 4];
            Bs[lq * 4 + 0][row] = vb.x; Bs[lq * 4 + 1][row] = vb.y;
            Bs[lq * 4 + 2][row] = vb.z; Bs[lq * 4 + 3][row] = vb.w;
        }
        __syncthreads();
#pragma unroll
        for (int kk = 0; kk < 32; ++kk) {
            float4 a4 = *(const float4*)&As[kk][ty * 4];
            float4 b4 = *(const float4*)&Bs[kk][tx * 4];
            float av[4] = {a4.x, a4.y, a4.z, a4.w};
            float bv[4] = {b4.x, b4.y, b4.z, b4.w};
#pragma unroll
            for (int i = 0; i < 4; ++i)
#pragma unroll
                for (int j = 0; j < 4; ++j) acc[i][j] += av[i] * bv[j];
        }
        __syncthreads();
    }
#pragma unroll
    for (int i = 0; i < 4; ++i) {
        float4 o = make_float4(acc[i][0], acc[i][1], acc[i][2], acc[i][3]);
        *(float4*)&Cm[(size_t)(m0 + ty * 4 + i) * ND + n0 + tx * 4] = o;
    }
}

// ---------------------------------------------------------------- K3: row-normalize proj, sq = sum(projN^2)
__global__ __launch_bounds__(256) void k_normalize(float* __restrict__ proj, float* __restrict__ sqv) {
    int r = blockIdx.x, tid = threadIdx.x;
    __shared__ double red[8];
    __shared__ float invs;
    float* row = proj + (size_t)r * ND;
    double s = 0.0;
    for (int d = tid; d < ND; d += 256) { double v = (double)row[d]; s += v * v; }
#pragma unroll
    for (int off = 32; off; off >>= 1) s += __shfl_down(s, off, 64);
    int wid = tid >> 6, lane = tid & 63;
    if (lane == 0) red[wid] = s;
    __syncthreads();
    if (tid == 0) invs = (float)(1.0 / fmax(sqrt(red[0] + red[1] + red[2] + red[3]), 1e-12));
    __syncthreads();
    float inv = invs;
    double s2 = 0.0;
    for (int d = tid; d < ND; d += 256) {
        float v = row[d] * inv; row[d] = v; s2 += (double)v * (double)v;
    }
#pragma unroll
    for (int off = 32; off; off >>= 1) s2 += __shfl_down(s2, off, 64);
    __syncthreads();
    if (lane == 0) red[wid] = s2;
    __syncthreads();
    if (tid == 0) sqv[r] = (float)(red[0] + red[1] + red[2] + red[3]);
}

// ---------------------------------------------------------------- K4: C init = with_floor(exp(-d2)), write d_hist[:,0]
__global__ __launch_bounds__(256) void k_pairwise(const float* __restrict__ proj,
                                                  const float* __restrict__ sqv,
                                                  float* __restrict__ dhist) {
    int b = blockIdx.x, tid = threadIdx.x;
    int tx = tid & 15, ty = tid >> 4;
    __shared__ float Ps[NN][65];
    float acc[5][5];
#pragma unroll
    for (int a = 0; a < 5; ++a)
#pragma unroll
        for (int c = 0; c < 5; ++c) acc[a][c] = 0.f;
    const float* Pb = proj + (size_t)b * NN * ND;
    for (int k0 = 0; k0 < ND; k0 += 64) {
        __syncthreads();
        for (int idx = tid; idx < NN * 64; idx += 256) {
            int i = idx >> 6, kk = idx & 63;
            Ps[i][kk] = Pb[(size_t)i * ND + k0 + kk];
        }
        __syncthreads();
        for (int kk = 0; kk < 64; ++kk) {
            float av[5], bv[5];
#pragma unroll
            for (int a = 0; a < 5; ++a) { int i = ty + 16 * a; av[a] = (i < NN) ? Ps[i][kk] : 0.f; }
#pragma unroll
            for (int c = 0; c < 5; ++c) { int j = tx + 16 * c; bv[c] = (j < NN) ? Ps[j][kk] : 0.f; }
#pragma unroll
            for (int a = 0; a < 5; ++a)
#pragma unroll
                for (int c = 0; c < 5; ++c) acc[a][c] += av[a] * bv[c];
        }
    }
#pragma unroll
    for (int a = 0; a < 5; ++a)
#pragma unroll
        for (int c = 0; c < 5; ++c) {
            int i = ty + 16 * a, j = tx + 16 * c;
            if (i < NN && j < NN) {
                float d2 = fmaxf(sqv[b * NN + i] + sqv[b * NN + j] - 2.0f * acc[a][c], 0.f);
                double cv = exp(-(double)d2);   // TAU = 1
                float cf = (i == j) ? 0.f : fmaxf((float)cv, FLOORV);
                dhist[(size_t)b * 9 * NN * NN + (size_t)i * NN + j] = cf;
            }
        }
}

// ---------------------------------------------------------------- helper: readlane broadcast (imm lane after unroll)
__device__ __forceinline__ float rl(float v, int l) {
    return __int_as_float(__builtin_amdgcn_readlane(__float_as_int(v), l));
}

// ---------------------------------------------------------------- K5: 8-step physarum dynamics
// Register-resident solve: wave 0 holds row i (=lane+1) of the 65x65 system
// entirely in VGPRs (A_[1..64] = columns, A_[65] = rhs; all indices static so
// the array stays in registers). Rank-1 Gaussian elimination, no pivoting
// (diag-dominant M-matrix): pivot-row broadcast is a single v_readlane per
// (k,j) element, folded into v_fmac as the SGPR operand. ZERO LDS traffic and
// ZERO barriers inside the solve (vs 16 barriers/step + Aug LDS RMW before).
// Frozen rows (lane < k) are protected by l=0 (cndmask, uniform code).
// Each lane captures its own diagonal reciprocal at its pivot round via a
// static (lane==k-1) select, so back-substitution needs no dynamic indexing.
// Row 0 (never modified) is eliminated first from a per-lane register copy of
// Cs row 0 (v0), also via readlane broadcast. 2 barriers/step remain:
// solve->update (pd ready) and update->next solve (Cs ready).
__global__ __launch_bounds__(256) void k_dynamics(float* __restrict__ dhist,
                                                  float* __restrict__ qhist,
                                                  double* __restrict__ part) {
    int b = blockIdx.x, tid = threadIdx.x;
    __shared__ float Cs[NN * NN];         // conductance fp32 (16.9 KB)
    __shared__ float pd[NN];              // potentials
    __shared__ double redd[8];
    float* C0 = dhist + (size_t)b * 9 * NN * NN;
    for (int t = tid; t < NN * NN; t += 256) Cs[t] = C0[t];
    __syncthreads();

    const int lane = tid;                 // valid when tid < 64
    const int i_own = tid + 1;            // row owned by this lane (1..64)
    double stable = 0.0, sparse = 0.0;

#pragma unroll 1
    for (int step = 0; step < NSTEPS; ++step) {
        if (tid < 64) {
            // ---- build row i_own in registers: A[i][j] = -C[i][j], diag = deg+eps
            const float* crow = Cs + (size_t)i_own * NN;
            float A_[66];
            float deg = 0.f, c0 = 0.f;
#pragma unroll
            for (int j = 0; j < 65; ++j) {
                float cv = crow[j];
                deg += cv;
                if (j == 0) c0 = cv; else A_[j] = -cv;
            }
            float diag = deg + EPSV;
#pragma unroll
            for (int j = 1; j < 65; ++j) A_[j] = (j == i_own) ? diag : A_[j];
            A_[65] = -(1.0f / 64.0f);     // rhs for rows >= 1

            // ---- round 0: pivot = row 0 (A[0][j] = -C[0][j], rhs0 = 1)
            float v0 = Cs[lane + 1];      // C[0][lane+1], also reused for p0 later
            float s0 = v0;
#pragma unroll
            for (int off = 1; off < 64; off <<= 1) s0 += __shfl_xor(s0, off, 64);
            float d0 = s0 + EPSV;         // A[0][0] (C[0][0] = 0)
            float invd0 = 1.0f / d0;
            float l0 = -c0 * invd0;       // A[i][0] / A[0][0]
#pragma unroll
            for (int j = 1; j < 65; ++j)
                A_[j] = __builtin_fmaf(l0, rl(v0, j - 1), A_[j]);  // -= l0 * (-C[0][j])
            A_[65] -= l0;                 // -= l0 * rhs0

            // ---- rounds 1..63 (k=64 only captures last diagonal)
            float inv_own = 0.f;
#pragma unroll
            for (int k = 1; k < 65; ++k) {
                float pk = rl(A_[k], k - 1);          // pivot diagonal (uniform)
                float invp = 1.0f / pk;
                inv_own = (lane == k - 1) ? invp : inv_own;
                if (k < 64) {
                    float l = (lane >= k) ? A_[k] * invp : 0.f;  // frozen rows: l=0
                    float ln = -l;
#pragma unroll
                    for (int j = k + 1; j < 66; ++j)
                        A_[j] = __builtin_fmaf(ln, rl(A_[j], k - 1), A_[j]);
                }
            }

            // ---- back substitution (register rows, shfl chain)
            float rhs = A_[65];
            float acc = 0.f, p_own = 0.f;
#pragma unroll
            for (int i = 64; i >= 1; --i) {
                float t = (rhs - acc) * inv_own;      // valid on lane i-1
                float pi = rl(t, i - 1);
                p_own = (i_own == i) ? t : p_own;
                acc = __builtin_fmaf((i_own < i) ? A_[i] : 0.f, pi, acc);
            }
            pd[i_own] = p_own;
            // p0 = (1 + sum_j C[0][j]*p_j) / d0  (row 0 never modified)
            float sp = v0 * p_own;
#pragma unroll
            for (int off = 1; off < 64; off <<= 1) sp += __shfl_xor(sp, off, 64);
            if (lane == 0) pd[0] = (1.0f + sp) * invd0;
        }
        __syncthreads();

        // ---- flow + conductance update (fp32, matches reference)
        float* qout = qhist + ((size_t)b * NSTEPS + step) * NN * NN;
        float* dout = dhist + ((size_t)b * 9 + step + 1) * NN * NN;
        for (int t = tid; t < NN * NN; t += 256) {
            int i = t / NN, j = t - i * NN;
            float c = Cs[t];
            float fl = c * (pd[i] - pd[j]);
            qout[t] = fl;
            float rr = fabsf(fl); rr = rr / (1.0f + rr);
            float cn = c + DTV * (rr - GAMMAV * c);
            float cnf = (i == j) ? 0.0f : fmaxf(cn, FLOORV);
            Cs[t] = cnf;
            dout[t] = cnf;
            stable += fabs((double)cnf - (double)c);
            if (step == NSTEPS - 1 && i > 0 && j > 0) sparse += (double)cnf;
        }
        __syncthreads();
    }

#pragma unroll
    for (int off = 32; off; off >>= 1) {
        stable += __shfl_down(stable, off, 64);
        sparse += __shfl_down(sparse, off, 64);
    }
    int wid = tid >> 6, lane63 = tid & 63;
    if (lane63 == 0) { redd[wid] = stable; redd[4 + wid] = sparse; }
    __syncthreads();
    if (tid == 0) {
        part[b]      = redd[4] + redd[5] + redd[6] + redd[7];
        part[NB + b] = redd[0] + redd[1] + redd[2] + redd[3];
    }
}

// ---------------------------------------------------------------- K6: scores, top-k masks, gid, group_scores
__global__ __launch_bounds__(256) void k_scores(const float* __restrict__ qhist,
                                                const float* __restrict__ local,
                                                const int* __restrict__ ghp,
                                                const int* __restrict__ gwp,
                                                float* __restrict__ keep,
                                                float* __restrict__ patch,
                                                float* __restrict__ gidout,
                                                float* __restrict__ gsout) {
    int b = blockIdx.x, tid = threadIdx.x;
    __shared__ double gf[NG];
    __shared__ double ts[NP];
    __shared__ double red[8];
    __shared__ double stats[2];
    if (tid < NG) {
        const float* qrow = qhist + ((size_t)b * NSTEPS + (NSTEPS - 1)) * NN * NN + (size_t)(tid + 1) * NN;
        double s = 0.0;
        for (int j = 0; j < NN; ++j) s += fabs((double)qrow[j]);
        gf[tid] = s;
    }
    __syncthreads();
    if (tid < 64) {
        double v = gf[tid];
        double s = v;
#pragma unroll
        for (int off = 32; off; off >>= 1) s += __shfl_down(s, off, 64);
        double mean = __shfl(s, 0, 64) / (double)NG;
        double d = v - mean, ss = d * d;
#pragma unroll
        for (int off = 32; off; off >>= 1) ss += __shfl_down(ss, off, 64);
        if (tid == 0) { stats[0] = mean; stats[1] = 1.0 / fmax(sqrt(ss / (NG - 1)), 1e-6); }
    }
    const float* lrow = local + (size_t)b * NP;
    double s1 = 0.0;
    for (int p = tid; p < NP; p += 256) s1 += (double)lrow[p];
#pragma unroll
    for (int off = 32; off; off >>= 1) s1 += __shfl_down(s1, off, 64);
    int wid = tid >> 6, lane = tid & 63;
    if (lane == 0) red[wid] = s1;
    __syncthreads();
    double lmean = (red[0] + red[1] + red[2] + red[3]) / (double)NP;
    double s2 = 0.0;
    for (int p = tid; p < NP; p += 256) { double d = (double)lrow[p] - lmean; s2 += d * d; }
#pragma unroll
    for (int off = 32; off; off >>= 1) s2 += __shfl_down(s2, off, 64);
    __syncthreads();
    if (lane == 0) red[wid] = s2;
    __syncthreads();
    double linv = 1.0 / fmax(sqrt((red[0] + red[1] + red[2] + red[3]) / (double)(NP - 1)), 1e-6);
    double gmean = stats[0], ginv = stats[1];
    int grid_h = *ghp, grid_w = *gwp;
    int gh = (grid_h + 7) / 8, gw = (grid_w + 7) / 8;
    for (int p = tid; p < NP; p += 256) {
        int row = p / grid_w, col = p - row * grid_w;
        int g = min(row / gh, 7) * 8 + min(col / gw, 7);
        double gsc = (gf[g] - gmean) * ginv;
        double lsc = ((double)lrow[p] - lmean) * linv;
        ts[p] = gsc + 0.5 * lsc;  // FLOW_W=1, LOCAL_W=0.5
        gidout[(size_t)b * NP + p] = (float)g;
        gsout[(size_t)b * NP + p]  = (float)gsc;
    }
    __syncthreads();
    for (int p = tid; p < NP; p += 256) {
        double sp = ts[p];
        int c = 0;
        for (int qq = 0; qq < NP; ++qq) {
            double v = ts[qq];
            c += (v > sp) || (v == sp && qq < p);
        }
        float kf = (c < KEEPC) ? 1.0f : 0.0f;
        patch[(size_t)b * NP + p] = kf;
        keep[(size_t)b * (NP + 1) + 1 + p] = kf;
    }
    if (tid == 0) keep[(size_t)b * (NP + 1)] = 1.0f;
}

// ---------------------------------------------------------------- K7: routing rows
__global__ void k_routing(const float* __restrict__ dhist, float* __restrict__ rout) {
    int b = blockIdx.x, tid = threadIdx.x;  // 64 threads
    const float* Crow = dhist + ((size_t)b * 9 + 8) * NN * NN + (size_t)(tid + 1) * NN + 1;
    double s = 0.0;
    for (int j = 0; j < NG; ++j) s += (double)Crow[j];
    double inv = 1.0 / fmax(s, 1e-6);
    float* orow = rout + ((size_t)b * NG + tid) * NG;
    for (int j = 0; j < NG; ++j) orow[j] = (float)((double)Crow[j] * inv);
}

// ---------------------------------------------------------------- K8: aux scalar reduction
__global__ void k_aux(const double* __restrict__ part, float* __restrict__ osp, float* __restrict__ ost) {
    int tid = threadIdx.x;  // 64 threads
    double sp = part[tid], st = part[NB + tid];
#pragma unroll
    for (int off = 32; off; off >>= 1) {
        sp += __shfl_down(sp, off, 64);
        st += __shfl_down(st, off, 64);
    }
    if (tid == 0) { *osp = (float)(sp / NB); *ost = (float)(st / NB); }
}

// ----------------------------------------------------------------
extern "C" void kernel_launch(void* const* d_in, const int* in_sizes, int n_in,
                              void* d_out, int out_size, void* d_ws, size_t ws_size,
                              hipStream_t stream) {
    const float* tokens = (const float*)d_in[0];
    const float* cls    = (const float*)d_in[1];
    const float* W      = (const float*)d_in[2];
    const float* local  = (const float*)d_in[3];
    const int* ghp = (const int*)d_in[4];
    const int* gwp = (const int*)d_in[5];

    float* out = (float*)d_out;
    float* o_keep  = out;                                   // NB x (NP+1)
    float* o_patch = o_keep + (size_t)NB * (NP + 1);        // NB x NP
    float* o_gid   = o_patch + (size_t)NB * NP;             // NB x NP
    float* o_gs    = o_gid + (size_t)NB * NP;               // NB x NP
    float* o_dh    = o_gs + (size_t)NB * NP;                // NB x 9 x NN x NN
    float* o_qh    = o_dh + (size_t)NB * 9 * NN * NN;       // NB x 8 x NN x NN
    float* o_rt    = o_qh + (size_t)NB * NSTEPS * NN * NN;  // NB x NG x NG
    float* o_sp    = o_rt + (size_t)NB * NG * NG;           // scalar
    float* o_st    = o_sp + 1;                              // scalar

    float* nodes = (float*)d_ws;                            // NB*NN x ND
    float* proj  = nodes + (size_t)NB * NN * ND;            // NB*NN x ND
    float* sqv   = proj + (size_t)NB * NN * ND;             // NB*NN
    double* part = (double*)(((uintptr_t)(sqv + NB * NN) + 15) & ~(uintptr_t)15);  // 2*NB

    k_group_means<<<NB * NN, 256, 0, stream>>>(tokens, cls, nodes, ghp, gwp);
    dim3 g2((NB * NN) / 64, ND / 64);
    k_gemm_nt<<<g2, 256, 0, stream>>>(nodes, W, proj);
    k_normalize<<<NB * NN, 256, 0, stream>>>(proj, sqv);
    k_pairwise<<<NB, 256, 0, stream>>>(proj, sqv, o_dh);
    k_dynamics<<<NB, 256, 0, stream>>>(o_dh, o_qh, part);
    k_scores<<<NB, 256, 0, stream>>>(o_qh, local, ghp, gwp, o_keep, o_patch, o_gid, o_gs);
    k_routing<<<NB, 64, 0, stream>>>(o_dh, o_rt);
    k_aux<<<1, 64, 0, stream>>>(part, o_sp, o_st);
}

// Round 2
// 975.035 us; speedup vs baseline: 1.1622x; 1.1622x over previous
//
#include <hip/hip_runtime.h>
#include <stdint.h>

#define NB 64      // batch
#define NP 576     // patches
#define ND 768     // dim
#define NG 64      // groups
#define NN 65      // groups + 1 (cls)
#define NSTEPS 8
#define FLOORV 1.0e-4f
#define EPSV   1.0e-4f
#define DTV    0.1f
#define GAMMAV 0.1f
#define KEEPC  288  // max(1, round(576*0.5))

// ---------------------------------------------------------------- K1: group means
__global__ __launch_bounds__(256) void k_group_means(const float* __restrict__ tokens,
                                                     const float* __restrict__ cls,
                                                     float* __restrict__ nodes,
                                                     const int* __restrict__ ghp,
                                                     const int* __restrict__ gwp) {
    int bx = blockIdx.x;
    int b = bx / NN, n = bx - b * NN;
    int tid = threadIdx.x;
    float* orow = nodes + (size_t)bx * ND;
    if (n == 0) {
        for (int d = tid; d < ND; d += 256) orow[d] = cls[(size_t)b * ND + d];
        return;
    }
    int grid_h = *ghp, grid_w = *gwp;
    int gh = (grid_h + 7) / 8, gw = (grid_w + 7) / 8;
    int g = n - 1, gr = g >> 3, gc = g & 7;
    int r0 = gr * gh, r1 = (gr == 7) ? grid_h : min((gr + 1) * gh, grid_h);
    int c0 = gc * gw, c1 = (gc == 7) ? grid_w : min((gc + 1) * gw, grid_w);
    int cnt = (r1 > r0 && c1 > c0) ? (r1 - r0) * (c1 - c0) : 0;
    float cf = (float)max(cnt, 1);
    const float* tb = tokens + (size_t)b * NP * ND;
    for (int d = tid; d < ND; d += 256) {
        float acc = 0.f;
        for (int r = r0; r < r1; ++r)
            for (int c = c0; c < c1; ++c)
                acc += tb[(size_t)(r * grid_w + c) * ND + d];
        orow[d] = acc / cf;
    }
}

// ---------------------------------------------------------------- K2: proj = nodes @ W^T (NT gemm)
__global__ __launch_bounds__(256) void k_gemm_nt(const float* __restrict__ A,
                                                 const float* __restrict__ Bm,
                                                 float* __restrict__ Cm) {
    __shared__ float As[32][68];
    __shared__ float Bs[32][68];
    int tid = threadIdx.x;
    int m0 = blockIdx.x * 64, n0 = blockIdx.y * 64;
    int tx = tid & 15, ty = tid >> 4;
    float acc[4][4];
#pragma unroll
    for (int i = 0; i < 4; ++i)
#pragma unroll
        for (int j = 0; j < 4; ++j) acc[i][j] = 0.f;
    int lrow = tid >> 3, lq = tid & 7;
    for (int k0 = 0; k0 < ND; k0 += 32) {
#pragma unroll
        for (int l = 0; l < 2; ++l) {
            int row = lrow + l * 32;
            float4 va = *(const float4*)&A[(size_t)(m0 + row) * ND + k0 + lq * 4];
            As[lq * 4 + 0][row] = va.x; As[lq * 4 + 1][row] = va.y;
            As[lq * 4 + 2][row] = va.z; As[lq * 4 + 3][row] = va.w;
            float4 vb = *(const float4*)&Bm[(size_t)(n0 + row) * ND + k0 + lq * 4];
            Bs[lq * 4 + 0][row] = vb.x; Bs[lq * 4 + 1][row] = vb.y;
            Bs[lq * 4 + 2][row] = vb.z; Bs[lq * 4 + 3][row] = vb.w;
        }
        __syncthreads();
#pragma unroll
        for (int kk = 0; kk < 32; ++kk) {
            float4 a4 = *(const float4*)&As[kk][ty * 4];
            float4 b4 = *(const float4*)&Bs[kk][tx * 4];
            float av[4] = {a4.x, a4.y, a4.z, a4.w};
            float bv[4] = {b4.x, b4.y, b4.z, b4.w};
#pragma unroll
            for (int i = 0; i < 4; ++i)
#pragma unroll
                for (int j = 0; j < 4; ++j) acc[i][j] += av[i] * bv[j];
        }
        __syncthreads();
    }
#pragma unroll
    for (int i = 0; i < 4; ++i) {
        float4 o = make_float4(acc[i][0], acc[i][1], acc[i][2], acc[i][3]);
        *(float4*)&Cm[(size_t)(m0 + ty * 4 + i) * ND + n0 + tx * 4] = o;
    }
}

// ---------------------------------------------------------------- K3: row-normalize proj, sq = sum(projN^2)
__global__ __launch_bounds__(256) void k_normalize(float* __restrict__ proj, float* __restrict__ sqv) {
    int r = blockIdx.x, tid = threadIdx.x;
    __shared__ double red[8];
    __shared__ float invs;
    float* row = proj + (size_t)r * ND;
    double s = 0.0;
    for (int d = tid; d < ND; d += 256) { double v = (double)row[d]; s += v * v; }
#pragma unroll
    for (int off = 32; off; off >>= 1) s += __shfl_down(s, off, 64);
    int wid = tid >> 6, lane = tid & 63;
    if (lane == 0) red[wid] = s;
    __syncthreads();
    if (tid == 0) invs = (float)(1.0 / fmax(sqrt(red[0] + red[1] + red[2] + red[3]), 1e-12));
    __syncthreads();
    float inv = invs;
    double s2 = 0.0;
    for (int d = tid; d < ND; d += 256) {
        float v = row[d] * inv; row[d] = v; s2 += (double)v * (double)v;
    }
#pragma unroll
    for (int off = 32; off; off >>= 1) s2 += __shfl_down(s2, off, 64);
    __syncthreads();
    if (lane == 0) red[wid] = s2;
    __syncthreads();
    if (tid == 0) sqv[r] = (float)(red[0] + red[1] + red[2] + red[3]);
}

// ---------------------------------------------------------------- K4: C init = with_floor(exp(-d2)), write d_hist[:,0]
__global__ __launch_bounds__(256) void k_pairwise(const float* __restrict__ proj,
                                                  const float* __restrict__ sqv,
                                                  float* __restrict__ dhist) {
    int b = blockIdx.x, tid = threadIdx.x;
    int tx = tid & 15, ty = tid >> 4;
    __shared__ float Ps[NN][65];
    float acc[5][5];
#pragma unroll
    for (int a = 0; a < 5; ++a)
#pragma unroll
        for (int c = 0; c < 5; ++c) acc[a][c] = 0.f;
    const float* Pb = proj + (size_t)b * NN * ND;
    for (int k0 = 0; k0 < ND; k0 += 64) {
        __syncthreads();
        for (int idx = tid; idx < NN * 64; idx += 256) {
            int i = idx >> 6, kk = idx & 63;
            Ps[i][kk] = Pb[(size_t)i * ND + k0 + kk];
        }
        __syncthreads();
        for (int kk = 0; kk < 64; ++kk) {
            float av[5], bv[5];
#pragma unroll
            for (int a = 0; a < 5; ++a) { int i = ty + 16 * a; av[a] = (i < NN) ? Ps[i][kk] : 0.f; }
#pragma unroll
            for (int c = 0; c < 5; ++c) { int j = tx + 16 * c; bv[c] = (j < NN) ? Ps[j][kk] : 0.f; }
#pragma unroll
            for (int a = 0; a < 5; ++a)
#pragma unroll
                for (int c = 0; c < 5; ++c) acc[a][c] += av[a] * bv[c];
        }
    }
#pragma unroll
    for (int a = 0; a < 5; ++a)
#pragma unroll
        for (int c = 0; c < 5; ++c) {
            int i = ty + 16 * a, j = tx + 16 * c;
            if (i < NN && j < NN) {
                float d2 = fmaxf(sqv[b * NN + i] + sqv[b * NN + j] - 2.0f * acc[a][c], 0.f);
                double cv = exp(-(double)d2);   // TAU = 1
                float cf = (i == j) ? 0.f : fmaxf((float)cv, FLOORV);
                dhist[(size_t)b * 9 * NN * NN + (size_t)i * NN + j] = cf;
            }
        }
}

// ---------------------------------------------------------------- helper: readlane broadcast (imm lane after unroll)
__device__ __forceinline__ float rl(float v, int l) {
    return __int_as_float(__builtin_amdgcn_readlane(__float_as_int(v), l));
}

// ---------------------------------------------------------------- K5: 8-step physarum dynamics
// ONE WAVE per batch (64 threads, zero __syncthreads). Lane L owns row L+1 of
// the 65x65 system entirely in VGPRs. All array indices are compile-time
// constants: the elimination inner loop runs j=2..65 with a CONSTANT bound and
// an `if (j > k)` predicate that constant-folds after full unroll (round 1's
// `j = k+1` start made the inner trip count depend on the outer induction var,
// which blocked inner-first unrolling -> A_[] demoted to scratch, VGPR=52,
// FETCH_SIZE 2.5x. This version must show VGPR ~90-120 = promotion proof).
// Pivot-row broadcast = v_readlane (imm lane), folded into v_fmac.
// Frozen rows (lane < k) use l=0 (cndmask, uniform code, folds dead at unroll).
// Wave-synchronous LDS handoffs (pd, Cs) fenced with __threadfence_block().
// Arithmetic is bit-identical to round 1's version, which PASSED correctness.
__global__ __launch_bounds__(64) void k_dynamics(float* __restrict__ dhist,
                                                 float* __restrict__ qhist,
                                                 double* __restrict__ part) {
    int b = blockIdx.x;
    int lane = threadIdx.x;               // 0..63, one full wave
    __shared__ float Cs[NN * NN];         // conductance fp32 (16.9 KB)
    __shared__ float pd[NN];              // potentials
    float* C0 = dhist + (size_t)b * 9 * NN * NN;
    for (int t = lane; t < NN * NN; t += 64) Cs[t] = C0[t];
    __threadfence_block();

    const int i_own = lane + 1;           // row owned by this lane (1..64)
    double stable = 0.0, sparse = 0.0;

#pragma unroll 1
    for (int step = 0; step < NSTEPS; ++step) {
        // ---- build row i_own in registers: A[i][j] = -C[i][j], diag = deg+eps
        const float* crow = Cs + (size_t)i_own * NN;
        float A_[66];
        float deg = 0.f, c0 = 0.f;
#pragma unroll
        for (int j = 0; j < 65; ++j) {
            float cv = crow[j];
            deg += cv;
            if (j == 0) c0 = cv; else A_[j] = -cv;
        }
        float diag = deg + EPSV;
#pragma unroll
        for (int j = 1; j < 65; ++j) A_[j] = (j == i_own) ? diag : A_[j];
        A_[65] = -(1.0f / 64.0f);         // rhs for rows >= 1

        // ---- round 0: pivot = row 0 (A[0][j] = -C[0][j], rhs0 = 1)
        float v0 = Cs[lane + 1];          // C[0][lane+1], reused for p0 later
        float s0 = v0;
#pragma unroll
        for (int off = 1; off < 64; off <<= 1) s0 += __shfl_xor(s0, off, 64);
        float d0 = s0 + EPSV;             // A[0][0] (C[0][0] = 0)
        float invd0 = 1.0f / d0;
        float l0 = -c0 * invd0;           // A[i][0] / A[0][0]
#pragma unroll
        for (int j = 1; j < 65; ++j)
            A_[j] = __builtin_fmaf(l0, rl(v0, j - 1), A_[j]);  // -= l0 * (-C[0][j])
        A_[65] -= l0;                     // -= l0 * rhs0

        // ---- rounds 1..63 (k=64 only captures last diagonal)
        float inv_own = 0.f;
#pragma unroll
        for (int k = 1; k < 65; ++k) {
            float pk = rl(A_[k], k - 1);          // pivot diagonal (uniform)
            float invp = 1.0f / pk;
            inv_own = (lane == k - 1) ? invp : inv_own;
            if (k < 64) {
                float l = (lane >= k) ? A_[k] * invp : 0.f;  // frozen rows: l=0
                float ln = -l;
#pragma unroll
                for (int j = 2; j < 66; ++j) {    // CONSTANT bounds; j>k folds
                    if (j > k)
                        A_[j] = __builtin_fmaf(ln, rl(A_[j], k - 1), A_[j]);
                }
            }
        }

        // ---- back substitution (register rows, readlane chain)
        float rhs = A_[65];
        float acc = 0.f, p_own = 0.f;
#pragma unroll
        for (int i = 64; i >= 1; --i) {
            float t = (rhs - acc) * inv_own;      // valid on lane i-1
            float pi = rl(t, i - 1);
            p_own = (i_own == i) ? t : p_own;
            acc = __builtin_fmaf((i_own < i) ? A_[i] : 0.f, pi, acc);
        }
        pd[i_own] = p_own;
        // p0 = (1 + sum_j C[0][j]*p_j) / d0  (row 0 never modified)
        float sp = v0 * p_own;
#pragma unroll
        for (int off = 1; off < 64; off <<= 1) sp += __shfl_xor(sp, off, 64);
        if (lane == 0) pd[0] = (1.0f + sp) * invd0;
        __threadfence_block();

        // ---- flow + conductance update (fp32, matches reference)
        float* qout = qhist + ((size_t)b * NSTEPS + step) * NN * NN;
        float* dout = dhist + ((size_t)b * 9 + step + 1) * NN * NN;
        for (int t = lane; t < NN * NN; t += 64) {
            int i = t / NN, j = t - i * NN;
            float c = Cs[t];
            float fl = c * (pd[i] - pd[j]);
            qout[t] = fl;
            float rr = fabsf(fl); rr = rr / (1.0f + rr);
            float cn = c + DTV * (rr - GAMMAV * c);
            float cnf = (i == j) ? 0.0f : fmaxf(cn, FLOORV);
            Cs[t] = cnf;
            dout[t] = cnf;
            stable += fabs((double)cnf - (double)c);
            if (step == NSTEPS - 1 && i > 0 && j > 0) sparse += (double)cnf;
        }
        __threadfence_block();
    }

#pragma unroll
    for (int off = 32; off; off >>= 1) {
        stable += __shfl_down(stable, off, 64);
        sparse += __shfl_down(sparse, off, 64);
    }
    if (lane == 0) {
        part[b]      = sparse;
        part[NB + b] = stable;
    }
}

// ---------------------------------------------------------------- K6: scores, top-k masks, gid, group_scores
__global__ __launch_bounds__(256) void k_scores(const float* __restrict__ qhist,
                                                const float* __restrict__ local,
                                                const int* __restrict__ ghp,
                                                const int* __restrict__ gwp,
                                                float* __restrict__ keep,
                                                float* __restrict__ patch,
                                                float* __restrict__ gidout,
                                                float* __restrict__ gsout) {
    int b = blockIdx.x, tid = threadIdx.x;
    __shared__ double gf[NG];
    __shared__ double ts[NP];
    __shared__ double red[8];
    __shared__ double stats[2];
    if (tid < NG) {
        const float* qrow = qhist + ((size_t)b * NSTEPS + (NSTEPS - 1)) * NN * NN + (size_t)(tid + 1) * NN;
        double s = 0.0;
        for (int j = 0; j < NN; ++j) s += fabs((double)qrow[j]);
        gf[tid] = s;
    }
    __syncthreads();
    if (tid < 64) {
        double v = gf[tid];
        double s = v;
#pragma unroll
        for (int off = 32; off; off >>= 1) s += __shfl_down(s, off, 64);
        double mean = __shfl(s, 0, 64) / (double)NG;
        double d = v - mean, ss = d * d;
#pragma unroll
        for (int off = 32; off; off >>= 1) ss += __shfl_down(ss, off, 64);
        if (tid == 0) { stats[0] = mean; stats[1] = 1.0 / fmax(sqrt(ss / (NG - 1)), 1e-6); }
    }
    const float* lrow = local + (size_t)b * NP;
    double s1 = 0.0;
    for (int p = tid; p < NP; p += 256) s1 += (double)lrow[p];
#pragma unroll
    for (int off = 32; off; off >>= 1) s1 += __shfl_down(s1, off, 64);
    int wid = tid >> 6, lane = tid & 63;
    if (lane == 0) red[wid] = s1;
    __syncthreads();
    double lmean = (red[0] + red[1] + red[2] + red[3]) / (double)NP;
    double s2 = 0.0;
    for (int p = tid; p < NP; p += 256) { double d = (double)lrow[p] - lmean; s2 += d * d; }
#pragma unroll
    for (int off = 32; off; off >>= 1) s2 += __shfl_down(s2, off, 64);
    __syncthreads();
    if (lane == 0) red[wid] = s2;
    __syncthreads();
    double linv = 1.0 / fmax(sqrt((red[0] + red[1] + red[2] + red[3]) / (double)(NP - 1)), 1e-6);
    double gmean = stats[0], ginv = stats[1];
    int grid_h = *ghp, grid_w = *gwp;
    int gh = (grid_h + 7) / 8, gw = (grid_w + 7) / 8;
    for (int p = tid; p < NP; p += 256) {
        int row = p / grid_w, col = p - row * grid_w;
        int g = min(row / gh, 7) * 8 + min(col / gw, 7);
        double gsc = (gf[g] - gmean) * ginv;
        double lsc = ((double)lrow[p] - lmean) * linv;
        ts[p] = gsc + 0.5 * lsc;  // FLOW_W=1, LOCAL_W=0.5
        gidout[(size_t)b * NP + p] = (float)g;
        gsout[(size_t)b * NP + p]  = (float)gsc;
    }
    __syncthreads();
    for (int p = tid; p < NP; p += 256) {
        double sp = ts[p];
        int c = 0;
        for (int qq = 0; qq < NP; ++qq) {
            double v = ts[qq];
            c += (v > sp) || (v == sp && qq < p);
        }
        float kf = (c < KEEPC) ? 1.0f : 0.0f;
        patch[(size_t)b * NP + p] = kf;
        keep[(size_t)b * (NP + 1) + 1 + p] = kf;
    }
    if (tid == 0) keep[(size_t)b * (NP + 1)] = 1.0f;
}

// ---------------------------------------------------------------- K7: routing rows
__global__ void k_routing(const float* __restrict__ dhist, float* __restrict__ rout) {
    int b = blockIdx.x, tid = threadIdx.x;  // 64 threads
    const float* Crow = dhist + ((size_t)b * 9 + 8) * NN * NN + (size_t)(tid + 1) * NN + 1;
    double s = 0.0;
    for (int j = 0; j < NG; ++j) s += (double)Crow[j];
    double inv = 1.0 / fmax(s, 1e-6);
    float* orow = rout + ((size_t)b * NG + tid) * NG;
    for (int j = 0; j < NG; ++j) orow[j] = (float)((double)Crow[j] * inv);
}

// ---------------------------------------------------------------- K8: aux scalar reduction
__global__ void k_aux(const double* __restrict__ part, float* __restrict__ osp, float* __restrict__ ost) {
    int tid = threadIdx.x;  // 64 threads
    double sp = part[tid], st = part[NB + tid];
#pragma unroll
    for (int off = 32; off; off >>= 1) {
        sp += __shfl_down(sp, off, 64);
        st += __shfl_down(st, off, 64);
    }
    if (tid == 0) { *osp = (float)(sp / NB); *ost = (float)(st / NB); }
}

// ----------------------------------------------------------------
extern "C" void kernel_launch(void* const* d_in, const int* in_sizes, int n_in,
                              void* d_out, int out_size, void* d_ws, size_t ws_size,
                              hipStream_t stream) {
    const float* tokens = (const float*)d_in[0];
    const float* cls    = (const float*)d_in[1];
    const float* W      = (const float*)d_in[2];
    const float* local  = (const float*)d_in[3];
    const int* ghp = (const int*)d_in[4];
    const int* gwp = (const int*)d_in[5];

    float* out = (float*)d_out;
    float* o_keep  = out;                                   // NB x (NP+1)
    float* o_patch = o_keep + (size_t)NB * (NP + 1);        // NB x NP
    float* o_gid   = o_patch + (size_t)NB * NP;             // NB x NP
    float* o_gs    = o_gid + (size_t)NB * NP;               // NB x NP
    float* o_dh    = o_gs + (size_t)NB * NP;                // NB x 9 x NN x NN
    float* o_qh    = o_dh + (size_t)NB * 9 * NN * NN;       // NB x 8 x NN x NN
    float* o_rt    = o_qh + (size_t)NB * NSTEPS * NN * NN;  // NB x NG x NG
    float* o_sp    = o_rt + (size_t)NB * NG * NG;           // scalar
    float* o_st    = o_sp + 1;                              // scalar

    float* nodes = (float*)d_ws;                            // NB*NN x ND
    float* proj  = nodes + (size_t)NB * NN * ND;            // NB*NN x ND
    float* sqv   = proj + (size_t)NB * NN * ND;             // NB*NN
    double* part = (double*)(((uintptr_t)(sqv + NB * NN) + 15) & ~(uintptr_t)15);  // 2*NB

    k_group_means<<<NB * NN, 256, 0, stream>>>(tokens, cls, nodes, ghp, gwp);
    dim3 g2((NB * NN) / 64, ND / 64);
    k_gemm_nt<<<g2, 256, 0, stream>>>(nodes, W, proj);
    k_normalize<<<NB * NN, 256, 0, stream>>>(proj, sqv);
    k_pairwise<<<NB, 256, 0, stream>>>(proj, sqv, o_dh);
    k_dynamics<<<NB, 64, 0, stream>>>(o_dh, o_qh, part);
    k_scores<<<NB, 256, 0, stream>>>(o_qh, local, ghp, gwp, o_keep, o_patch, o_gid, o_gs);
    k_routing<<<NB, 64, 0, stream>>>(o_dh, o_rt);
    k_aux<<<1, 64, 0, stream>>>(part, o_sp, o_st);
}

// Round 3
// 705.865 us; speedup vs baseline: 1.6053x; 1.3813x over previous
//
#include <hip/hip_runtime.h>
#include <stdint.h>

#define NB 64      // batch
#define NP 576     // patches
#define ND 768     // dim
#define NG 64      // groups
#define NN 65      // groups + 1 (cls)
#define NSTEPS 8
#define FLOORV 1.0e-4f
#define EPSV   1.0e-4f
#define DTV    0.1f
#define GAMMAV 0.1f
#define KEEPC  288  // max(1, round(576*0.5))

// ---------------------------------------------------------------- K1: group means
__global__ __launch_bounds__(256) void k_group_means(const float* __restrict__ tokens,
                                                     const float* __restrict__ cls,
                                                     float* __restrict__ nodes,
                                                     const int* __restrict__ ghp,
                                                     const int* __restrict__ gwp) {
    int bx = blockIdx.x;
    int b = bx / NN, n = bx - b * NN;
    int tid = threadIdx.x;
    float* orow = nodes + (size_t)bx * ND;
    if (n == 0) {
        for (int d = tid; d < ND; d += 256) orow[d] = cls[(size_t)b * ND + d];
        return;
    }
    int grid_h = *ghp, grid_w = *gwp;
    int gh = (grid_h + 7) / 8, gw = (grid_w + 7) / 8;
    int g = n - 1, gr = g >> 3, gc = g & 7;
    int r0 = gr * gh, r1 = (gr == 7) ? grid_h : min((gr + 1) * gh, grid_h);
    int c0 = gc * gw, c1 = (gc == 7) ? grid_w : min((gc + 1) * gw, grid_w);
    int cnt = (r1 > r0 && c1 > c0) ? (r1 - r0) * (c1 - c0) : 0;
    float cf = (float)max(cnt, 1);
    const float* tb = tokens + (size_t)b * NP * ND;
    for (int d = tid; d < ND; d += 256) {
        float acc = 0.f;
        for (int r = r0; r < r1; ++r)
            for (int c = c0; c < c1; ++c)
                acc += tb[(size_t)(r * grid_w + c) * ND + d];
        orow[d] = acc / cf;
    }
}

// ---------------------------------------------------------------- K2: proj = nodes @ W^T (NT gemm)
__global__ __launch_bounds__(256) void k_gemm_nt(const float* __restrict__ A,
                                                 const float* __restrict__ Bm,
                                                 float* __restrict__ Cm) {
    __shared__ float As[32][68];
    __shared__ float Bs[32][68];
    int tid = threadIdx.x;
    int m0 = blockIdx.x * 64, n0 = blockIdx.y * 64;
    int tx = tid & 15, ty = tid >> 4;
    float acc[4][4];
#pragma unroll
    for (int i = 0; i < 4; ++i)
#pragma unroll
        for (int j = 0; j < 4; ++j) acc[i][j] = 0.f;
    int lrow = tid >> 3, lq = tid & 7;
    for (int k0 = 0; k0 < ND; k0 += 32) {
#pragma unroll
        for (int l = 0; l < 2; ++l) {
            int row = lrow + l * 32;
            float4 va = *(const float4*)&A[(size_t)(m0 + row) * ND + k0 + lq * 4];
            As[lq * 4 + 0][row] = va.x; As[lq * 4 + 1][row] = va.y;
            As[lq * 4 + 2][row] = va.z; As[lq * 4 + 3][row] = va.w;
            float4 vb = *(const float4*)&Bm[(size_t)(n0 + row) * ND + k0 + lq * 4];
            Bs[lq * 4 + 0][row] = vb.x; Bs[lq * 4 + 1][row] = vb.y;
            Bs[lq * 4 + 2][row] = vb.z; Bs[lq * 4 + 3][row] = vb.w;
        }
        __syncthreads();
#pragma unroll
        for (int kk = 0; kk < 32; ++kk) {
            float4 a4 = *(const float4*)&As[kk][ty * 4];
            float4 b4 = *(const float4*)&Bs[kk][tx * 4];
            float av[4] = {a4.x, a4.y, a4.z, a4.w};
            float bv[4] = {b4.x, b4.y, b4.z, b4.w};
#pragma unroll
            for (int i = 0; i < 4; ++i)
#pragma unroll
                for (int j = 0; j < 4; ++j) acc[i][j] += av[i] * bv[j];
        }
        __syncthreads();
    }
#pragma unroll
    for (int i = 0; i < 4; ++i) {
        float4 o = make_float4(acc[i][0], acc[i][1], acc[i][2], acc[i][3]);
        *(float4*)&Cm[(size_t)(m0 + ty * 4 + i) * ND + n0 + tx * 4] = o;
    }
}

// ---------------------------------------------------------------- K3: row-normalize proj, sq = sum(projN^2)
__global__ __launch_bounds__(256) void k_normalize(float* __restrict__ proj, float* __restrict__ sqv) {
    int r = blockIdx.x, tid = threadIdx.x;
    __shared__ double red[8];
    __shared__ float invs;
    float* row = proj + (size_t)r * ND;
    double s = 0.0;
    for (int d = tid; d < ND; d += 256) { double v = (double)row[d]; s += v * v; }
#pragma unroll
    for (int off = 32; off; off >>= 1) s += __shfl_down(s, off, 64);
    int wid = tid >> 6, lane = tid & 63;
    if (lane == 0) red[wid] = s;
    __syncthreads();
    if (tid == 0) invs = (float)(1.0 / fmax(sqrt(red[0] + red[1] + red[2] + red[3]), 1e-12));
    __syncthreads();
    float inv = invs;
    double s2 = 0.0;
    for (int d = tid; d < ND; d += 256) {
        float v = row[d] * inv; row[d] = v; s2 += (double)v * (double)v;
    }
#pragma unroll
    for (int off = 32; off; off >>= 1) s2 += __shfl_down(s2, off, 64);
    __syncthreads();
    if (lane == 0) red[wid] = s2;
    __syncthreads();
    if (tid == 0) sqv[r] = (float)(red[0] + red[1] + red[2] + red[3]);
}

// ---------------------------------------------------------------- K4: C init = with_floor(exp(-d2)), write d_hist[:,0]
__global__ __launch_bounds__(256) void k_pairwise(const float* __restrict__ proj,
                                                  const float* __restrict__ sqv,
                                                  float* __restrict__ dhist) {
    int b = blockIdx.x, tid = threadIdx.x;
    int tx = tid & 15, ty = tid >> 4;
    __shared__ float Ps[NN][65];
    float acc[5][5];
#pragma unroll
    for (int a = 0; a < 5; ++a)
#pragma unroll
        for (int c = 0; c < 5; ++c) acc[a][c] = 0.f;
    const float* Pb = proj + (size_t)b * NN * ND;
    for (int k0 = 0; k0 < ND; k0 += 64) {
        __syncthreads();
        for (int idx = tid; idx < NN * 64; idx += 256) {
            int i = idx >> 6, kk = idx & 63;
            Ps[i][kk] = Pb[(size_t)i * ND + k0 + kk];
        }
        __syncthreads();
        for (int kk = 0; kk < 64; ++kk) {
            float av[5], bv[5];
#pragma unroll
            for (int a = 0; a < 5; ++a) { int i = ty + 16 * a; av[a] = (i < NN) ? Ps[i][kk] : 0.f; }
#pragma unroll
            for (int c = 0; c < 5; ++c) { int j = tx + 16 * c; bv[c] = (j < NN) ? Ps[j][kk] : 0.f; }
#pragma unroll
            for (int a = 0; a < 5; ++a)
#pragma unroll
                for (int c = 0; c < 5; ++c) acc[a][c] += av[a] * bv[c];
        }
    }
#pragma unroll
    for (int a = 0; a < 5; ++a)
#pragma unroll
        for (int c = 0; c < 5; ++c) {
            int i = ty + 16 * a, j = tx + 16 * c;
            if (i < NN && j < NN) {
                float d2 = fmaxf(sqv[b * NN + i] + sqv[b * NN + j] - 2.0f * acc[a][c], 0.f);
                double cv = exp(-(double)d2);   // TAU = 1
                float cf = (i == j) ? 0.f : fmaxf((float)cv, FLOORV);
                dhist[(size_t)b * 9 * NN * NN + (size_t)i * NN + j] = cf;
            }
        }
}

// ---------------------------------------------------------------- helper: readlane broadcast (imm lane after unroll)
__device__ __forceinline__ float rl(float v, int l) {
    return __int_as_float(__builtin_amdgcn_readlane(__float_as_int(v), l));
}

// Template-recursive Gaussian elimination: K is a TEMPLATE parameter, so
// there is no outer loop in the IR; every A[] index and readlane lane id is a
// compile-time literal in every instantiation. This is the structural fix for
// rounds 1-2 where `#pragma unroll` declined to unroll the outer k-loop (body
// too large), leaving dynamic indices A_[k] -> SROA demoted A_ to scratch
// (VGPR=52/72, wave stalled on L2-resident scratch, 155K cy/step).
template<int K> struct ElimStep {
    static __device__ __forceinline__ void run(float (&A)[66], int lane, float& inv_own) {
        float pk = rl(A[K], K - 1);            // pivot diagonal (uniform)
        float invp = 1.0f / pk;
        inv_own = (lane == K - 1) ? invp : inv_own;
        if constexpr (K < 64) {
            float l = (lane >= K) ? A[K] * invp : 0.f;   // frozen rows: l=0
            float ln = -l;
#pragma unroll
            for (int j = K + 1; j < 66; ++j)   // constant bounds per instantiation
                A[j] = __builtin_fmaf(ln, rl(A[j], K - 1), A[j]);
        }
        ElimStep<K + 1>::run(A, lane, inv_own);
    }
};
template<> struct ElimStep<65> {
    static __device__ __forceinline__ void run(float (&)[66], int, float&) {}
};

template<int I> struct BackStep {
    static __device__ __forceinline__ void run(const float (&A)[66], int i_own, float inv_own,
                                               float rhs, float& acc, float& p_own) {
        float t = (rhs - acc) * inv_own;       // valid on lane I-1
        float pi = rl(t, I - 1);
        p_own = (i_own == I) ? t : p_own;
        acc = __builtin_fmaf((i_own < I) ? A[I] : 0.f, pi, acc);
        BackStep<I - 1>::run(A, i_own, inv_own, rhs, acc, p_own);
    }
};
template<> struct BackStep<0> {
    static __device__ __forceinline__ void run(const float (&)[66], int, float, float, float&, float&) {}
};

// ---------------------------------------------------------------- K5: 8-step physarum dynamics
// ONE WAVE per batch (64 threads, zero __syncthreads). Lane L owns row L+1 of
// the 65x65 system entirely in VGPRs (template-forced promotion, see above).
// Pivot-row broadcast = v_readlane (literal lane), folded into v_fmac.
// Wave-synchronous LDS handoffs (pd, Cs) fenced with __threadfence_block().
// Arithmetic is bit-identical to rounds 1-2, both of which PASSED correctness.
__global__ __launch_bounds__(64) void k_dynamics(float* __restrict__ dhist,
                                                 float* __restrict__ qhist,
                                                 double* __restrict__ part) {
    int b = blockIdx.x;
    int lane = threadIdx.x;               // 0..63, one full wave
    __shared__ float Cs[NN * NN];         // conductance fp32 (16.9 KB)
    __shared__ float pd[NN];              // potentials
    float* C0 = dhist + (size_t)b * 9 * NN * NN;
    for (int t = lane; t < NN * NN; t += 64) Cs[t] = C0[t];
    __threadfence_block();

    const int i_own = lane + 1;           // row owned by this lane (1..64)
    double stable = 0.0, sparse = 0.0;

#pragma unroll 1
    for (int step = 0; step < NSTEPS; ++step) {
        // ---- build row i_own in registers: A[i][j] = -C[i][j], diag = deg+eps
        const float* crow = Cs + (size_t)i_own * NN;
        float A_[66];
        float deg = 0.f, c0 = 0.f;
#pragma unroll
        for (int j = 0; j < 65; ++j) {
            float cv = crow[j];
            deg += cv;
            if (j == 0) c0 = cv; else A_[j] = -cv;
        }
        float diag = deg + EPSV;
#pragma unroll
        for (int j = 1; j < 65; ++j) A_[j] = (j == i_own) ? diag : A_[j];
        A_[65] = -(1.0f / 64.0f);         // rhs for rows >= 1

        // ---- round 0: pivot = row 0 (A[0][j] = -C[0][j], rhs0 = 1)
        float v0 = Cs[lane + 1];          // C[0][lane+1], reused for p0 later
        float s0 = v0;
#pragma unroll
        for (int off = 1; off < 64; off <<= 1) s0 += __shfl_xor(s0, off, 64);
        float d0 = s0 + EPSV;             // A[0][0] (C[0][0] = 0)
        float invd0 = 1.0f / d0;
        float l0 = -c0 * invd0;           // A[i][0] / A[0][0]
#pragma unroll
        for (int j = 1; j < 65; ++j)
            A_[j] = __builtin_fmaf(l0, rl(v0, j - 1), A_[j]);  // -= l0 * (-C[0][j])
        A_[65] -= l0;                     // -= l0 * rhs0

        // ---- rounds 1..64 (template-unrolled; k=64 only captures last diagonal)
        float inv_own = 0.f;
        ElimStep<1>::run(A_, lane, inv_own);

        // ---- back substitution (register rows, readlane chain)
        float rhs = A_[65];
        float acc = 0.f, p_own = 0.f;
        BackStep<64>::run(A_, i_own, inv_own, rhs, acc, p_own);
        pd[i_own] = p_own;
        // p0 = (1 + sum_j C[0][j]*p_j) / d0  (row 0 never modified)
        float sp = v0 * p_own;
#pragma unroll
        for (int off = 1; off < 64; off <<= 1) sp += __shfl_xor(sp, off, 64);
        if (lane == 0) pd[0] = (1.0f + sp) * invd0;
        __threadfence_block();

        // ---- flow + conductance update (fp32, matches reference)
        float* qout = qhist + ((size_t)b * NSTEPS + step) * NN * NN;
        float* dout = dhist + ((size_t)b * 9 + step + 1) * NN * NN;
        for (int t = lane; t < NN * NN; t += 64) {
            int i = t / NN, j = t - i * NN;
            float c = Cs[t];
            float fl = c * (pd[i] - pd[j]);
            qout[t] = fl;
            float rr = fabsf(fl); rr = rr / (1.0f + rr);
            float cn = c + DTV * (rr - GAMMAV * c);
            float cnf = (i == j) ? 0.0f : fmaxf(cn, FLOORV);
            Cs[t] = cnf;
            dout[t] = cnf;
            stable += fabs((double)cnf - (double)c);
            if (step == NSTEPS - 1 && i > 0 && j > 0) sparse += (double)cnf;
        }
        __threadfence_block();
    }

#pragma unroll
    for (int off = 32; off; off >>= 1) {
        stable += __shfl_down(stable, off, 64);
        sparse += __shfl_down(sparse, off, 64);
    }
    if (lane == 0) {
        part[b]      = sparse;
        part[NB + b] = stable;
    }
}

// ---------------------------------------------------------------- K6: scores, top-k masks, gid, group_scores
__global__ __launch_bounds__(256) void k_scores(const float* __restrict__ qhist,
                                                const float* __restrict__ local,
                                                const int* __restrict__ ghp,
                                                const int* __restrict__ gwp,
                                                float* __restrict__ keep,
                                                float* __restrict__ patch,
                                                float* __restrict__ gidout,
                                                float* __restrict__ gsout) {
    int b = blockIdx.x, tid = threadIdx.x;
    __shared__ double gf[NG];
    __shared__ double ts[NP];
    __shared__ double red[8];
    __shared__ double stats[2];
    if (tid < NG) {
        const float* qrow = qhist + ((size_t)b * NSTEPS + (NSTEPS - 1)) * NN * NN + (size_t)(tid + 1) * NN;
        double s = 0.0;
        for (int j = 0; j < NN; ++j) s += fabs((double)qrow[j]);
        gf[tid] = s;
    }
    __syncthreads();
    if (tid < 64) {
        double v = gf[tid];
        double s = v;
#pragma unroll
        for (int off = 32; off; off >>= 1) s += __shfl_down(s, off, 64);
        double mean = __shfl(s, 0, 64) / (double)NG;
        double d = v - mean, ss = d * d;
#pragma unroll
        for (int off = 32; off; off >>= 1) ss += __shfl_down(ss, off, 64);
        if (tid == 0) { stats[0] = mean; stats[1] = 1.0 / fmax(sqrt(ss / (NG - 1)), 1e-6); }
    }
    const float* lrow = local + (size_t)b * NP;
    double s1 = 0.0;
    for (int p = tid; p < NP; p += 256) s1 += (double)lrow[p];
#pragma unroll
    for (int off = 32; off; off >>= 1) s1 += __shfl_down(s1, off, 64);
    int wid = tid >> 6, lane = tid & 63;
    if (lane == 0) red[wid] = s1;
    __syncthreads();
    double lmean = (red[0] + red[1] + red[2] + red[3]) / (double)NP;
    double s2 = 0.0;
    for (int p = tid; p < NP; p += 256) { double d = (double)lrow[p] - lmean; s2 += d * d; }
#pragma unroll
    for (int off = 32; off; off >>= 1) s2 += __shfl_down(s2, off, 64);
    __syncthreads();
    if (lane == 0) red[wid] = s2;
    __syncthreads();
    double linv = 1.0 / fmax(sqrt((red[0] + red[1] + red[2] + red[3]) / (double)(NP - 1)), 1e-6);
    double gmean = stats[0], ginv = stats[1];
    int grid_h = *ghp, grid_w = *gwp;
    int gh = (grid_h + 7) / 8, gw = (grid_w + 7) / 8;
    for (int p = tid; p < NP; p += 256) {
        int row = p / grid_w, col = p - row * grid_w;
        int g = min(row / gh, 7) * 8 + min(col / gw, 7);
        double gsc = (gf[g] - gmean) * ginv;
        double lsc = ((double)lrow[p] - lmean) * linv;
        ts[p] = gsc + 0.5 * lsc;  // FLOW_W=1, LOCAL_W=0.5
        gidout[(size_t)b * NP + p] = (float)g;
        gsout[(size_t)b * NP + p]  = (float)gsc;
    }
    __syncthreads();
    for (int p = tid; p < NP; p += 256) {
        double sp = ts[p];
        int c = 0;
        for (int qq = 0; qq < NP; ++qq) {
            double v = ts[qq];
            c += (v > sp) || (v == sp && qq < p);
        }
        float kf = (c < KEEPC) ? 1.0f : 0.0f;
        patch[(size_t)b * NP + p] = kf;
        keep[(size_t)b * (NP + 1) + 1 + p] = kf;
    }
    if (tid == 0) keep[(size_t)b * (NP + 1)] = 1.0f;
}

// ---------------------------------------------------------------- K7: routing rows
__global__ void k_routing(const float* __restrict__ dhist, float* __restrict__ rout) {
    int b = blockIdx.x, tid = threadIdx.x;  // 64 threads
    const float* Crow = dhist + ((size_t)b * 9 + 8) * NN * NN + (size_t)(tid + 1) * NN + 1;
    double s = 0.0;
    for (int j = 0; j < NG; ++j) s += (double)Crow[j];
    double inv = 1.0 / fmax(s, 1e-6);
    float* orow = rout + ((size_t)b * NG + tid) * NG;
    for (int j = 0; j < NG; ++j) orow[j] = (float)((double)Crow[j] * inv);
}

// ---------------------------------------------------------------- K8: aux scalar reduction
__global__ void k_aux(const double* __restrict__ part, float* __restrict__ osp, float* __restrict__ ost) {
    int tid = threadIdx.x;  // 64 threads
    double sp = part[tid], st = part[NB + tid];
#pragma unroll
    for (int off = 32; off; off >>= 1) {
        sp += __shfl_down(sp, off, 64);
        st += __shfl_down(st, off, 64);
    }
    if (tid == 0) { *osp = (float)(sp / NB); *ost = (float)(st / NB); }
}

// ----------------------------------------------------------------
extern "C" void kernel_launch(void* const* d_in, const int* in_sizes, int n_in,
                              void* d_out, int out_size, void* d_ws, size_t ws_size,
                              hipStream_t stream) {
    const float* tokens = (const float*)d_in[0];
    const float* cls    = (const float*)d_in[1];
    const float* W      = (const float*)d_in[2];
    const float* local  = (const float*)d_in[3];
    const int* ghp = (const int*)d_in[4];
    const int* gwp = (const int*)d_in[5];

    float* out = (float*)d_out;
    float* o_keep  = out;                                   // NB x (NP+1)
    float* o_patch = o_keep + (size_t)NB * (NP + 1);        // NB x NP
    float* o_gid   = o_patch + (size_t)NB * NP;             // NB x NP
    float* o_gs    = o_gid + (size_t)NB * NP;               // NB x NP
    float* o_dh    = o_gs + (size_t)NB * NP;                // NB x 9 x NN x NN
    float* o_qh    = o_dh + (size_t)NB * 9 * NN * NN;       // NB x 8 x NN x NN
    float* o_rt    = o_qh + (size_t)NB * NSTEPS * NN * NN;  // NB x NG x NG
    float* o_sp    = o_rt + (size_t)NB * NG * NG;           // scalar
    float* o_st    = o_sp + 1;                              // scalar

    float* nodes = (float*)d_ws;                            // NB*NN x ND
    float* proj  = nodes + (size_t)NB * NN * ND;            // NB*NN x ND
    float* sqv   = proj + (size_t)NB * NN * ND;             // NB*NN
    double* part = (double*)(((uintptr_t)(sqv + NB * NN) + 15) & ~(uintptr_t)15);  // 2*NB

    k_group_means<<<NB * NN, 256, 0, stream>>>(tokens, cls, nodes, ghp, gwp);
    dim3 g2((NB * NN) / 64, ND / 64);
    k_gemm_nt<<<g2, 256, 0, stream>>>(nodes, W, proj);
    k_normalize<<<NB * NN, 256, 0, stream>>>(proj, sqv);
    k_pairwise<<<NB, 256, 0, stream>>>(proj, sqv, o_dh);
    k_dynamics<<<NB, 64, 0, stream>>>(o_dh, o_qh, part);
    k_scores<<<NB, 256, 0, stream>>>(o_qh, local, ghp, gwp, o_keep, o_patch, o_gid, o_gs);
    k_routing<<<NB, 64, 0, stream>>>(o_dh, o_rt);
    k_aux<<<1, 64, 0, stream>>>(part, o_sp, o_st);
}

// Round 5
// 704.899 us; speedup vs baseline: 1.6075x; 1.0014x over previous
//
#include <hip/hip_runtime.h>
#include <stdint.h>

#define NB 64      // batch
#define NP 576     // patches
#define ND 768     // dim
#define NG 64      // groups
#define NN 65      // groups + 1 (cls)
#define NSTEPS 8
#define FLOORV 1.0e-4f
#define EPSV   1.0e-4f
#define DTV    0.1f
#define GAMMAV 0.1f
#define KEEPC  288  // max(1, round(576*0.5))

// ---------------------------------------------------------------- K1: group means
__global__ __launch_bounds__(256) void k_group_means(const float* __restrict__ tokens,
                                                     const float* __restrict__ cls,
                                                     float* __restrict__ nodes,
                                                     const int* __restrict__ ghp,
                                                     const int* __restrict__ gwp) {
    int bx = blockIdx.x;
    int b = bx / NN, n = bx - b * NN;
    int tid = threadIdx.x;
    float* orow = nodes + (size_t)bx * ND;
    if (n == 0) {
        for (int d = tid; d < ND; d += 256) orow[d] = cls[(size_t)b * ND + d];
        return;
    }
    int grid_h = *ghp, grid_w = *gwp;
    int gh = (grid_h + 7) / 8, gw = (grid_w + 7) / 8;
    int g = n - 1, gr = g >> 3, gc = g & 7;
    int r0 = gr * gh, r1 = (gr == 7) ? grid_h : min((gr + 1) * gh, grid_h);
    int c0 = gc * gw, c1 = (gc == 7) ? grid_w : min((gc + 1) * gw, grid_w);
    int cnt = (r1 > r0 && c1 > c0) ? (r1 - r0) * (c1 - c0) : 0;
    float cf = (float)max(cnt, 1);
    const float* tb = tokens + (size_t)b * NP * ND;
    for (int d = tid; d < ND; d += 256) {
        float acc = 0.f;
        for (int r = r0; r < r1; ++r)
            for (int c = c0; c < c1; ++c)
                acc += tb[(size_t)(r * grid_w + c) * ND + d];
        orow[d] = acc / cf;
    }
}

// ---------------------------------------------------------------- K2: proj = nodes @ W^T (NT gemm)
__global__ __launch_bounds__(256) void k_gemm_nt(const float* __restrict__ A,
                                                 const float* __restrict__ Bm,
                                                 float* __restrict__ Cm) {
    __shared__ float As[32][68];
    __shared__ float Bs[32][68];
    int tid = threadIdx.x;
    int m0 = blockIdx.x * 64, n0 = blockIdx.y * 64;
    int tx = tid & 15, ty = tid >> 4;
    float acc[4][4];
#pragma unroll
    for (int i = 0; i < 4; ++i)
#pragma unroll
        for (int j = 0; j < 4; ++j) acc[i][j] = 0.f;
    int lrow = tid >> 3, lq = tid & 7;
    for (int k0 = 0; k0 < ND; k0 += 32) {
#pragma unroll
        for (int l = 0; l < 2; ++l) {
            int row = lrow + l * 32;
            float4 va = *(const float4*)&A[(size_t)(m0 + row) * ND + k0 + lq * 4];
            As[lq * 4 + 0][row] = va.x; As[lq * 4 + 1][row] = va.y;
            As[lq * 4 + 2][row] = va.z; As[lq * 4 + 3][row] = va.w;
            float4 vb = *(const float4*)&Bm[(size_t)(n0 + row) * ND + k0 + lq * 4];
            Bs[lq * 4 + 0][row] = vb.x; Bs[lq * 4 + 1][row] = vb.y;
            Bs[lq * 4 + 2][row] = vb.z; Bs[lq * 4 + 3][row] = vb.w;
        }
        __syncthreads();
#pragma unroll
        for (int kk = 0; kk < 32; ++kk) {
            float4 a4 = *(const float4*)&As[kk][ty * 4];
            float4 b4 = *(const float4*)&Bs[kk][tx * 4];
            float av[4] = {a4.x, a4.y, a4.z, a4.w};
            float bv[4] = {b4.x, b4.y, b4.z, b4.w};
#pragma unroll
            for (int i = 0; i < 4; ++i)
#pragma unroll
                for (int j = 0; j < 4; ++j) acc[i][j] += av[i] * bv[j];
        }
        __syncthreads();
    }
#pragma unroll
    for (int i = 0; i < 4; ++i) {
        float4 o = make_float4(acc[i][0], acc[i][1], acc[i][2], acc[i][3]);
        *(float4*)&Cm[(size_t)(m0 + ty * 4 + i) * ND + n0 + tx * 4] = o;
    }
}

// ---------------------------------------------------------------- K3: row-normalize proj, sq = sum(projN^2)
__global__ __launch_bounds__(256) void k_normalize(float* __restrict__ proj, float* __restrict__ sqv) {
    int r = blockIdx.x, tid = threadIdx.x;
    __shared__ double red[8];
    __shared__ float invs;
    float* row = proj + (size_t)r * ND;
    double s = 0.0;
    for (int d = tid; d < ND; d += 256) { double v = (double)row[d]; s += v * v; }
#pragma unroll
    for (int off = 32; off; off >>= 1) s += __shfl_down(s, off, 64);
    int wid = tid >> 6, lane = tid & 63;
    if (lane == 0) red[wid] = s;
    __syncthreads();
    if (tid == 0) invs = (float)(1.0 / fmax(sqrt(red[0] + red[1] + red[2] + red[3]), 1e-12));
    __syncthreads();
    float inv = invs;
    double s2 = 0.0;
    for (int d = tid; d < ND; d += 256) {
        float v = row[d] * inv; row[d] = v; s2 += (double)v * (double)v;
    }
#pragma unroll
    for (int off = 32; off; off >>= 1) s2 += __shfl_down(s2, off, 64);
    __syncthreads();
    if (lane == 0) red[wid] = s2;
    __syncthreads();
    if (tid == 0) sqv[r] = (float)(red[0] + red[1] + red[2] + red[3]);
}

// ---------------------------------------------------------------- K4: C init = with_floor(exp(-d2)), write d_hist[:,0]
__global__ __launch_bounds__(256) void k_pairwise(const float* __restrict__ proj,
                                                  const float* __restrict__ sqv,
                                                  float* __restrict__ dhist) {
    int b = blockIdx.x, tid = threadIdx.x;
    int tx = tid & 15, ty = tid >> 4;
    __shared__ float Ps[NN][65];
    float acc[5][5];
#pragma unroll
    for (int a = 0; a < 5; ++a)
#pragma unroll
        for (int c = 0; c < 5; ++c) acc[a][c] = 0.f;
    const float* Pb = proj + (size_t)b * NN * ND;
    for (int k0 = 0; k0 < ND; k0 += 64) {
        __syncthreads();
        for (int idx = tid; idx < NN * 64; idx += 256) {
            int i = idx >> 6, kk = idx & 63;
            Ps[i][kk] = Pb[(size_t)i * ND + k0 + kk];
        }
        __syncthreads();
        for (int kk = 0; kk < 64; ++kk) {
            float av[5], bv[5];
#pragma unroll
            for (int a = 0; a < 5; ++a) { int i = ty + 16 * a; av[a] = (i < NN) ? Ps[i][kk] : 0.f; }
#pragma unroll
            for (int c = 0; c < 5; ++c) { int j = tx + 16 * c; bv[c] = (j < NN) ? Ps[j][kk] : 0.f; }
#pragma unroll
            for (int a = 0; a < 5; ++a)
#pragma unroll
                for (int c = 0; c < 5; ++c) acc[a][c] += av[a] * bv[c];
        }
    }
#pragma unroll
    for (int a = 0; a < 5; ++a)
#pragma unroll
        for (int c = 0; c < 5; ++c) {
            int i = ty + 16 * a, j = tx + 16 * c;
            if (i < NN && j < NN) {
                float d2 = fmaxf(sqv[b * NN + i] + sqv[b * NN + j] - 2.0f * acc[a][c], 0.f);
                double cv = exp(-(double)d2);   // TAU = 1
                float cf = (i == j) ? 0.f : fmaxf((float)cv, FLOORV);
                dhist[(size_t)b * 9 * NN * NN + (size_t)i * NN + j] = cf;
            }
        }
}

// ---------------------------------------------------------------- helper: readlane broadcast (imm lane after unroll)
__device__ __forceinline__ float rl(float v, int l) {
    return __int_as_float(__builtin_amdgcn_readlane(__float_as_int(v), l));
}

// Template-recursive Gaussian elimination: K is a TEMPLATE parameter, so
// there is no outer loop in the IR; every A[] index and readlane lane id is a
// compile-time literal in every instantiation.
template<int K> struct ElimStep {
    static __device__ __forceinline__ void run(float (&A)[66], int lane, float& inv_own) {
        float pk = rl(A[K], K - 1);            // pivot diagonal (uniform)
        float invp = 1.0f / pk;
        inv_own = (lane == K - 1) ? invp : inv_own;
        if constexpr (K < 64) {
            float l = (lane >= K) ? A[K] * invp : 0.f;   // frozen rows: l=0
            float ln = -l;
#pragma unroll
            for (int j = K + 1; j < 66; ++j)   // constant bounds per instantiation
                A[j] = __builtin_fmaf(ln, rl(A[j], K - 1), A[j]);
        }
        ElimStep<K + 1>::run(A, lane, inv_own);
    }
};
template<> struct ElimStep<65> {
    static __device__ __forceinline__ void run(float (&)[66], int, float&) {}
};

template<int I> struct BackStep {
    static __device__ __forceinline__ void run(const float (&A)[66], int i_own, float inv_own,
                                               float rhs, float& acc, float& p_own) {
        float t = (rhs - acc) * inv_own;       // valid on lane I-1
        float pi = rl(t, I - 1);
        p_own = (i_own == I) ? t : p_own;
        acc = __builtin_fmaf((i_own < I) ? A[I] : 0.f, pi, acc);
        BackStep<I - 1>::run(A, i_own, inv_own, rhs, acc, p_own);
    }
};
template<> struct BackStep<0> {
    static __device__ __forceinline__ void run(const float (&)[66], int, float, float, float&, float&) {}
};

// ---------------------------------------------------------------- K5: 8-step physarum dynamics
// ONE WAVE per batch (64 threads, zero __syncthreads). Lane L owns row L+1 of
// the 65x65 system in VGPRs.
// ROUND 4/5 FIX: __launch_bounds__(64, 1) -- min-waves-per-EU = 1. Rounds 1-3
// all capped at 52/72/68 VGPRs (= the allocator's default ~8-waves/EU budget
// of 512/8 = 64 VGPRs) and spilled A_[] to scratch regardless of code
// structure. This kernel runs 64 blocks x 1 wave on 256 CUs -- occupancy is
// irrelevant -- so grant the allocator the full 512-VGPR budget.
// (Round 4 never ran: container-acquisition infra failure. Resubmitted as-is.)
// Arithmetic is bit-identical to rounds 1-3, all of which PASSED correctness.
__global__ __launch_bounds__(64, 1) void k_dynamics(float* __restrict__ dhist,
                                                    float* __restrict__ qhist,
                                                    double* __restrict__ part) {
    int b = blockIdx.x;
    int lane = threadIdx.x;               // 0..63, one full wave
    __shared__ float Cs[NN * NN];         // conductance fp32 (16.9 KB)
    __shared__ float pd[NN];              // potentials
    float* C0 = dhist + (size_t)b * 9 * NN * NN;
    for (int t = lane; t < NN * NN; t += 64) Cs[t] = C0[t];
    __threadfence_block();

    const int i_own = lane + 1;           // row owned by this lane (1..64)
    double stable = 0.0, sparse = 0.0;

#pragma unroll 1
    for (int step = 0; step < NSTEPS; ++step) {
        // ---- build row i_own in registers: A[i][j] = -C[i][j], diag = deg+eps
        const float* crow = Cs + (size_t)i_own * NN;
        float A_[66];
        float deg = 0.f, c0 = 0.f;
#pragma unroll
        for (int j = 0; j < 65; ++j) {
            float cv = crow[j];
            deg += cv;
            if (j == 0) c0 = cv; else A_[j] = -cv;
        }
        float diag = deg + EPSV;
#pragma unroll
        for (int j = 1; j < 65; ++j) A_[j] = (j == i_own) ? diag : A_[j];
        A_[65] = -(1.0f / 64.0f);         // rhs for rows >= 1

        // ---- round 0: pivot = row 0 (A[0][j] = -C[0][j], rhs0 = 1)
        float v0 = Cs[lane + 1];          // C[0][lane+1], reused for p0 later
        float s0 = v0;
#pragma unroll
        for (int off = 1; off < 64; off <<= 1) s0 += __shfl_xor(s0, off, 64);
        float d0 = s0 + EPSV;             // A[0][0] (C[0][0] = 0)
        float invd0 = 1.0f / d0;
        float l0 = -c0 * invd0;           // A[i][0] / A[0][0]
#pragma unroll
        for (int j = 1; j < 65; ++j)
            A_[j] = __builtin_fmaf(l0, rl(v0, j - 1), A_[j]);  // -= l0 * (-C[0][j])
        A_[65] -= l0;                     // -= l0 * rhs0

        // ---- rounds 1..64 (template-unrolled; k=64 only captures last diagonal)
        float inv_own = 0.f;
        ElimStep<1>::run(A_, lane, inv_own);

        // ---- back substitution (register rows, readlane chain)
        float rhs = A_[65];
        float acc = 0.f, p_own = 0.f;
        BackStep<64>::run(A_, i_own, inv_own, rhs, acc, p_own);
        pd[i_own] = p_own;
        // p0 = (1 + sum_j C[0][j]*p_j) / d0  (row 0 never modified)
        float sp = v0 * p_own;
#pragma unroll
        for (int off = 1; off < 64; off <<= 1) sp += __shfl_xor(sp, off, 64);
        if (lane == 0) pd[0] = (1.0f + sp) * invd0;
        __threadfence_block();

        // ---- flow + conductance update (fp32, matches reference)
        float* qout = qhist + ((size_t)b * NSTEPS + step) * NN * NN;
        float* dout = dhist + ((size_t)b * 9 + step + 1) * NN * NN;
        for (int t = lane; t < NN * NN; t += 64) {
            int i = t / NN, j = t - i * NN;
            float c = Cs[t];
            float fl = c * (pd[i] - pd[j]);
            qout[t] = fl;
            float rr = fabsf(fl); rr = rr / (1.0f + rr);
            float cn = c + DTV * (rr - GAMMAV * c);
            float cnf = (i == j) ? 0.0f : fmaxf(cn, FLOORV);
            Cs[t] = cnf;
            dout[t] = cnf;
            stable += fabs((double)cnf - (double)c);
            if (step == NSTEPS - 1 && i > 0 && j > 0) sparse += (double)cnf;
        }
        __threadfence_block();
    }

#pragma unroll
    for (int off = 32; off; off >>= 1) {
        stable += __shfl_down(stable, off, 64);
        sparse += __shfl_down(sparse, off, 64);
    }
    if (lane == 0) {
        part[b]      = sparse;
        part[NB + b] = stable;
    }
}

// ---------------------------------------------------------------- K6: scores, top-k masks, gid, group_scores
__global__ __launch_bounds__(256) void k_scores(const float* __restrict__ qhist,
                                                const float* __restrict__ local,
                                                const int* __restrict__ ghp,
                                                const int* __restrict__ gwp,
                                                float* __restrict__ keep,
                                                float* __restrict__ patch,
                                                float* __restrict__ gidout,
                                                float* __restrict__ gsout) {
    int b = blockIdx.x, tid = threadIdx.x;
    __shared__ double gf[NG];
    __shared__ double ts[NP];
    __shared__ double red[8];
    __shared__ double stats[2];
    if (tid < NG) {
        const float* qrow = qhist + ((size_t)b * NSTEPS + (NSTEPS - 1)) * NN * NN + (size_t)(tid + 1) * NN;
        double s = 0.0;
        for (int j = 0; j < NN; ++j) s += fabs((double)qrow[j]);
        gf[tid] = s;
    }
    __syncthreads();
    if (tid < 64) {
        double v = gf[tid];
        double s = v;
#pragma unroll
        for (int off = 32; off; off >>= 1) s += __shfl_down(s, off, 64);
        double mean = __shfl(s, 0, 64) / (double)NG;
        double d = v - mean, ss = d * d;
#pragma unroll
        for (int off = 32; off; off >>= 1) ss += __shfl_down(ss, off, 64);
        if (tid == 0) { stats[0] = mean; stats[1] = 1.0 / fmax(sqrt(ss / (NG - 1)), 1e-6); }
    }
    const float* lrow = local + (size_t)b * NP;
    double s1 = 0.0;
    for (int p = tid; p < NP; p += 256) s1 += (double)lrow[p];
#pragma unroll
    for (int off = 32; off; off >>= 1) s1 += __shfl_down(s1, off, 64);
    int wid = tid >> 6, lane = tid & 63;
    if (lane == 0) red[wid] = s1;
    __syncthreads();
    double lmean = (red[0] + red[1] + red[2] + red[3]) / (double)NP;
    double s2 = 0.0;
    for (int p = tid; p < NP; p += 256) { double d = (double)lrow[p] - lmean; s2 += d * d; }
#pragma unroll
    for (int off = 32; off; off >>= 1) s2 += __shfl_down(s2, off, 64);
    __syncthreads();
    if (lane == 0) red[wid] = s2;
    __syncthreads();
    double linv = 1.0 / fmax(sqrt((red[0] + red[1] + red[2] + red[3]) / (double)(NP - 1)), 1e-6);
    double gmean = stats[0], ginv = stats[1];
    int grid_h = *ghp, grid_w = *gwp;
    int gh = (grid_h + 7) / 8, gw = (grid_w + 7) / 8;
    for (int p = tid; p < NP; p += 256) {
        int row = p / grid_w, col = p - row * grid_w;
        int g = min(row / gh, 7) * 8 + min(col / gw, 7);
        double gsc = (gf[g] - gmean) * ginv;
        double lsc = ((double)lrow[p] - lmean) * linv;
        ts[p] = gsc + 0.5 * lsc;  // FLOW_W=1, LOCAL_W=0.5
        gidout[(size_t)b * NP + p] = (float)g;
        gsout[(size_t)b * NP + p]  = (float)gsc;
    }
    __syncthreads();
    for (int p = tid; p < NP; p += 256) {
        double sp = ts[p];
        int c = 0;
        for (int qq = 0; qq < NP; ++qq) {
            double v = ts[qq];
            c += (v > sp) || (v == sp && qq < p);
        }
        float kf = (c < KEEPC) ? 1.0f : 0.0f;
        patch[(size_t)b * NP + p] = kf;
        keep[(size_t)b * (NP + 1) + 1 + p] = kf;
    }
    if (tid == 0) keep[(size_t)b * (NP + 1)] = 1.0f;
}

// ---------------------------------------------------------------- K7: routing rows
__global__ void k_routing(const float* __restrict__ dhist, float* __restrict__ rout) {
    int b = blockIdx.x, tid = threadIdx.x;  // 64 threads
    const float* Crow = dhist + ((size_t)b * 9 + 8) * NN * NN + (size_t)(tid + 1) * NN + 1;
    double s = 0.0;
    for (int j = 0; j < NG; ++j) s += (double)Crow[j];
    double inv = 1.0 / fmax(s, 1e-6);
    float* orow = rout + ((size_t)b * NG + tid) * NG;
    for (int j = 0; j < NG; ++j) orow[j] = (float)((double)Crow[j] * inv);
}

// ---------------------------------------------------------------- K8: aux scalar reduction
__global__ void k_aux(const double* __restrict__ part, float* __restrict__ osp, float* __restrict__ ost) {
    int tid = threadIdx.x;  // 64 threads
    double sp = part[tid], st = part[NB + tid];
#pragma unroll
    for (int off = 32; off; off >>= 1) {
        sp += __shfl_down(sp, off, 64);
        st += __shfl_down(st, off, 64);
    }
    if (tid == 0) { *osp = (float)(sp / NB); *ost = (float)(st / NB); }
}

// ----------------------------------------------------------------
extern "C" void kernel_launch(void* const* d_in, const int* in_sizes, int n_in,
                              void* d_out, int out_size, void* d_ws, size_t ws_size,
                              hipStream_t stream) {
    const float* tokens = (const float*)d_in[0];
    const float* cls    = (const float*)d_in[1];
    const float* W      = (const float*)d_in[2];
    const float* local  = (const float*)d_in[3];
    const int* ghp = (const int*)d_in[4];
    const int* gwp = (const int*)d_in[5];

    float* out = (float*)d_out;
    float* o_keep  = out;                                   // NB x (NP+1)
    float* o_patch = o_keep + (size_t)NB * (NP + 1);        // NB x NP
    float* o_gid   = o_patch + (size_t)NB * NP;             // NB x NP
    float* o_gs    = o_gid + (size_t)NB * NP;               // NB x NP
    float* o_dh    = o_gs + (size_t)NB * NP;                // NB x 9 x NN x NN
    float* o_qh    = o_dh + (size_t)NB * 9 * NN * NN;       // NB x 8 x NN x NN
    float* o_rt    = o_qh + (size_t)NB * NSTEPS * NN * NN;  // NB x NG x NG
    float* o_sp    = o_rt + (size_t)NB * NG * NG;           // scalar
    float* o_st    = o_sp + 1;                              // scalar

    float* nodes = (float*)d_ws;                            // NB*NN x ND
    float* proj  = nodes + (size_t)NB * NN * ND;            // NB*NN x ND
    float* sqv   = proj + (size_t)NB * NN * ND;             // NB*NN
    double* part = (double*)(((uintptr_t)(sqv + NB * NN) + 15) & ~(uintptr_t)15);  // 2*NB

    k_group_means<<<NB * NN, 256, 0, stream>>>(tokens, cls, nodes, ghp, gwp);
    dim3 g2((NB * NN) / 64, ND / 64);
    k_gemm_nt<<<g2, 256, 0, stream>>>(nodes, W, proj);
    k_normalize<<<NB * NN, 256, 0, stream>>>(proj, sqv);
    k_pairwise<<<NB, 256, 0, stream>>>(proj, sqv, o_dh);
    k_dynamics<<<NB, 64, 0, stream>>>(o_dh, o_qh, part);
    k_scores<<<NB, 256, 0, stream>>>(o_qh, local, ghp, gwp, o_keep, o_patch, o_gid, o_gs);
    k_routing<<<NB, 64, 0, stream>>>(o_dh, o_rt);
    k_aux<<<1, 64, 0, stream>>>(part, o_sp, o_st);
}